// Round 1
// baseline (228.419 us; speedup 1.0000x reference)
//
#include <hip/hip_runtime.h>

// WindowWarp: B=256, T=2048, C=64, WINDOW_RATIO=0.1, SCALES={0.5,2.0}
// WARP_SIZE = ceil(0.1*2048) = 205
// L_MAX = T - WARP_SIZE + int(WARP_SIZE*2.0) = 1843 + 410 = 2253
constexpr int Bn     = 256;
constexpr int Tn     = 2048;
constexpr int Cn     = 64;
constexpr int WARPSZ = 205;
constexpr int LMAX   = 2253;

// Map intermediate index j -> source position s -> (i0, i1, frac) into x rows.
__device__ __forceinline__ void map_j(float jf, float start, float nl, float rdenom,
                                      int& i0, int& i1, float& fr) {
    bool in_win = (jf >= start) && (jf < start + nl);
    bool after  = (jf >= start + nl);
    float s_win   = start + (jf - start) * rdenom;      // rdenom = (WARP-1)/max(nl-1,1)
    float s_after = jf - nl + (float)WARPSZ;
    float s = in_win ? s_win : (after ? s_after : jf);
    s = fminf(fmaxf(s, 0.0f), (float)(Tn - 1));
    float p0 = floorf(s);
    fr = s - p0;
    i0 = (int)p0;
    i1 = min(i0 + 1, Tn - 1);
}

__global__ __launch_bounds__(256) void window_warp_kernel(
        const float* __restrict__ x,
        const float* __restrict__ scales,
        const int*   __restrict__ starts,
        float*       __restrict__ out) {
    int tid = blockIdx.x * 256 + threadIdx.x;
    int row = tid >> 4;          // (b, t) pair; 16 threads (float4 each) cover C=64
    int cg  = tid & 15;
    int b   = row >> 11;         // T = 2048 = 2^11
    int t   = row & (Tn - 1);

    float scale = scales[b];
    float start = (float)starts[b];
    float nl    = floorf((float)WARPSZ * scale);        // new_len
    float Lm1   = (float)(Tn - WARPSZ) + nl - 1.0f;     // L - 1

    // Stage 2 (resample) index: u = t*(L-1)/(T-1), clipped to [0, L-1]
    float u = ((float)t * Lm1) / (float)(Tn - 1);
    u = fminf(fmaxf(u, 0.0f), Lm1);
    float q0 = floorf(u);
    float fu = u - q0;
    int j0 = (int)q0;
    int j1 = min(j0 + 1, LMAX - 1);

    float rdenom = (float)(WARPSZ - 1) / fmaxf(nl - 1.0f, 1.0f);

    int i00, i01, i10, i11;
    float f0, f1;
    map_j((float)j0, start, nl, rdenom, i00, i01, f0);
    map_j((float)j1, start, nl, rdenom, i10, i11, f1);

    const float4* xb = (const float4*)(x + (size_t)b * Tn * Cn);
    float4 a0 = xb[(size_t)i00 * 16 + cg];
    float4 a1 = xb[(size_t)i01 * 16 + cg];
    float4 b0 = xb[(size_t)i10 * 16 + cg];
    float4 b1 = xb[(size_t)i11 * 16 + cg];

    // Stage-wise lerp matching reference arithmetic shape
    float g0 = 1.0f - f0, g1 = 1.0f - f1, gu = 1.0f - fu;
    float4 v0, v1, r;
    v0.x = a0.x * g0 + a1.x * f0;  v0.y = a0.y * g0 + a1.y * f0;
    v0.z = a0.z * g0 + a1.z * f0;  v0.w = a0.w * g0 + a1.w * f0;
    v1.x = b0.x * g1 + b1.x * f1;  v1.y = b0.y * g1 + b1.y * f1;
    v1.z = b0.z * g1 + b1.z * f1;  v1.w = b0.w * g1 + b1.w * f1;
    r.x = v0.x * gu + v1.x * fu;   r.y = v0.y * gu + v1.y * fu;
    r.z = v0.z * gu + v1.z * fu;   r.w = v0.w * gu + v1.w * fu;

    ((float4*)out)[(size_t)row * 16 + cg] = r;
}

extern "C" void kernel_launch(void* const* d_in, const int* in_sizes, int n_in,
                              void* d_out, int out_size, void* d_ws, size_t ws_size,
                              hipStream_t stream) {
    const float* x      = (const float*)d_in[0];
    const float* scales = (const float*)d_in[1];
    const int*   starts = (const int*)d_in[2];
    float* out = (float*)d_out;

    // B*T rows, 16 threads per row -> B*T*16 threads
    int total_threads = Bn * Tn * (Cn / 4);
    int blocks = total_threads / 256;
    window_warp_kernel<<<blocks, 256, 0, stream>>>(x, scales, starts, out);
}